// Round 1
// baseline (103.380 us; speedup 1.0000x reference)
//
#include <hip/hip_runtime.h>
#include <stdint.h>

// Kendall rank correlation, ProtoLayer: out[b,q,p] =
//   sum_{i<j} sign(q[b,q,j]-q[b,q,i]) * sign(pf[b,p,j]-pf[b,p,i]) / n_pairs
//
// Bit trick: with no exact ties, sign(a)*sign(b) = +1 iff (a>0)==(b>0).
// Pack 64 pair predicates per wave with __ballot; mismatches via popc(xor).
// Padding lanes (i>=j) are forced to 0 in BOTH q and p ballots -> xor=0,
// counted as "match"; the closed form  S = n_pairs - 2*M  (M = total
// mismatch popcount) is independent of padding.

#define BB 4
#define QQ 75
#define PP 5
#define DD 640          // = 10 chunks * 64 lanes
#define NCH 10
#define NPAIRS 204480   // DD*(DD-1)/2
#define SEG 4           // j-residue segments per (b,q) row
#define THREADS 1024    // 16 waves

__global__ __launch_bounds__(THREADS, 4)
void kendall_kernel(const float* __restrict__ qfeat,
                    const float* __restrict__ pfeat,
                    float* __restrict__ out) {
    __shared__ float qlds[DD];
    __shared__ float plds[PP * DD];
    __shared__ unsigned red[16][PP];

    const int tid  = threadIdx.x;
    const int lane = tid & 63;
    const int wave = tid >> 6;

    const int blk = blockIdx.x;
    const int s   = blk & (SEG - 1);
    const int bq  = blk >> 2;         // SEG == 4
    const int b   = bq / QQ;
    const int q   = bq % QQ;

    // Stage the query row and the 5 prototype rows for this batch into LDS.
    const float* qrow = qfeat + (size_t)(b * QQ + q) * DD;
    const float* prow = pfeat + (size_t)b * PP * DD;
    if (tid < DD) qlds[tid] = qrow[tid];
    for (int idx = tid; idx < PP * DD; idx += THREADS) plds[idx] = prow[idx];
    __syncthreads();

    // Lane-cached "i" values for every chunk (static indexing -> registers).
    float qi[NCH];
    float pi[PP][NCH];
#pragma unroll
    for (int c = 0; c < NCH; ++c) {
        qi[c] = qlds[c * 64 + lane];
#pragma unroll
        for (int p = 0; p < PP; ++p) pi[p][c] = plds[p * DD + c * 64 + lane];
    }

    // This wave owns all j with (j mod 64) == r.
    const int r = s + SEG * wave;     // in [0,64)

    unsigned m[PP];
#pragma unroll
    for (int p = 0; p < PP; ++p) m[p] = 0u;

    for (int k = 0; k < NCH; ++k) {
        const int j = 64 * k + r;
        const float qj = qlds[j];     // uniform broadcast reads
        float pj[PP];
#pragma unroll
        for (int p = 0; p < PP; ++p) pj[p] = plds[p * DD + j];

#pragma unroll
        for (int c = 0; c < NCH; ++c) {
            if (c < k) {
                // full chunk: all 64 lanes are valid (i = c*64+lane < j)
                unsigned long long bqm = __ballot(qj > qi[c]);
#pragma unroll
                for (int p = 0; p < PP; ++p) {
                    unsigned long long bpm = __ballot(pj[p] > pi[p][c]);
                    m[p] += (unsigned)__popcll(bqm ^ bpm);
                }
            } else if (c == k && r > 0) {
                // partial chunk: only lanes with i < j (lane < r) are valid
                const bool v = lane < r;
                unsigned long long bqm = __ballot(v && (qj > qi[c]));
#pragma unroll
                for (int p = 0; p < PP; ++p) {
                    unsigned long long bpm = __ballot(v && (pj[p] > pi[p][c]));
                    m[p] += (unsigned)__popcll(bqm ^ bpm);
                }
            }
        }
    }

    // Ballot results are lane-uniform -> every lane holds the same m[].
    if (lane == 0) {
#pragma unroll
        for (int p = 0; p < PP; ++p) red[wave][p] = m[p];
    }
    __syncthreads();

    if (tid < PP) {
        unsigned tot = 0;
        for (int w = 0; w < 16; ++w) tot += red[w][tid];
        // per-block contribution: 1/SEG - 2*M_seg/NPAIRS  (sums to the result)
        const float contrib =
            1.0f / (float)SEG - 2.0f * (float)tot * (1.0f / (float)NPAIRS);
        atomicAdd(&out[(b * QQ + q) * PP + tid], contrib);
    }
}

extern "C" void kernel_launch(void* const* d_in, const int* in_sizes, int n_in,
                              void* d_out, int out_size, void* d_ws, size_t ws_size,
                              hipStream_t stream) {
    const float* qfeat = (const float*)d_in[0];   // (B,Q,D) f32
    const float* pfeat = (const float*)d_in[1];   // (B,P,D) f32
    float* out = (float*)d_out;                   // (B,Q,P) f32

    // d_out is poisoned before every launch; blocks accumulate with atomics.
    hipMemsetAsync(out, 0, (size_t)out_size * sizeof(float), stream);

    const int grid = BB * QQ * SEG;               // 1200 blocks
    kendall_kernel<<<grid, THREADS, 0, stream>>>(qfeat, pfeat, out);
}

// Round 2
// 86.531 us; speedup vs baseline: 1.1947x; 1.1947x over previous
//
#include <hip/hip_runtime.h>
#include <stdint.h>

// Kendall rank correlation via bit-packed sign vectors.
//
// out[b,q,p] = sum_{i<j} sign(q_j - q_i) * sign(p_j - p_i) / NPAIRS
//            = 1 - 2*M/NPAIRS,  M = #pairs where the predicates (x_j > x_i)
//              differ between the query row and the prototype row.
//
// Packing layout (identical for q and p, which is all that matters):
//   word (gj, ig) held by lane l: j = 64*gj + l,  bit t covers i = 32*ig + t
//   ig in [0, 2*gj+2) -> 110 word-groups per row, 225280 bits, 204480 valid.
//   Diagonal groups (ig >= 2*gj) mask bits with i >= j to 0 in BOTH q and p,
//   so they xor to 0 and never count as mismatches.
//
// Hot loop is pure VALU: x_i is wave-uniform (SGPR via s_load), x_j is a
// per-lane VGPR -> one v_cmp per 64 predicates; mismatch accumulation is
// per-lane v_xor + v_bcnt (no SALU, no LDS reads -- round-1's bottlenecks).

#define BB 4
#define QQ 75
#define PP 5
#define DD 640
#define NPAIRS 204480
#define NGROUPS 110          // sum_{gj=0}^{9} (2*gj+2)
#define NROWS_P (BB * PP)    // 20
#define K2SEGS 4
#define K2WAVES 4            // 256 threads
#define K2SLOTS (K2SEGS * K2WAVES)

// ws usage: NGROUPS * NROWS_P * 64 * 4 B = 563,200 bytes of d_ws.

__device__ __forceinline__ unsigned pack_word(const float* __restrict__ row,
                                              int gj, int ig, float xj, int lane) {
    const float* __restrict__ xi = row + 32 * ig;  // wave-uniform base -> s_load
    unsigned w = 0;
    if (ig < 2 * gj) {
        // full group: all i = 32*ig + t are < 64*gj <= j
#pragma unroll
        for (int t = 0; t < 32; ++t)
            w = (w << 1) | (xi[t] < xj ? 1u : 0u);
    } else {
        // diagonal group: bit valid only when i < j  <=>  lane > off + t
        const int off = (ig - 2 * gj) * 32;
#pragma unroll
        for (int t = 0; t < 32; ++t)
            w = (w << 1) | ((xi[t] < xj && lane > off + t) ? 1u : 0u);
    }
    return w;
}

// K1: pack the 20 prototype rows into d_ws. Layout pm[G][row][lane] (u32) so
// K2's 5 per-proto loads are lane-coalesced with stride 64.
__global__ __launch_bounds__(64)
void pack_p_kernel(const float* __restrict__ pfeat, unsigned* __restrict__ pm) {
    const int lane = threadIdx.x;
    const int rp   = blockIdx.x;   // 0..19  (b*5 + p)
    const int slot = blockIdx.y;   // 0..7
    const float* row = pfeat + (size_t)rp * DD;
    int G = 0;
    for (int gj = 0; gj < 10; ++gj) {
        const float xj = row[64 * gj + lane];
        for (int ig = 0; ig < 2 * gj + 2; ++ig, ++G) {
            if ((G & 7) != slot) continue;   // uniform branch
            pm[((size_t)G * NROWS_P + rp) * 64 + lane] =
                pack_word(row, gj, ig, xj, lane);
        }
    }
}

// K2: fused q-pack + xor-popcount. One block per (b,q,word-segment).
__global__ __launch_bounds__(256)
void kendall_kernel(const float* __restrict__ qfeat,
                    const unsigned* __restrict__ pm,
                    float* __restrict__ out) {
    __shared__ unsigned red[K2WAVES][PP];

    const int tid  = threadIdx.x;
    const int lane = tid & 63;
    const int wave = tid >> 6;

    const int bx   = blockIdx.x;
    const int seg  = bx & (K2SEGS - 1);
    const int bq   = bx >> 2;            // K2SEGS == 4
    const int b    = bq / QQ;
    const int slot = seg * K2WAVES + wave;   // [0, 16)

    const float* row = qfeat + (size_t)bq * DD;

    unsigned m[PP] = {0u, 0u, 0u, 0u, 0u};

    int G = 0;
    for (int gj = 0; gj < 10; ++gj) {
        const float xj = row[64 * gj + lane];   // per-lane VGPR
        for (int ig = 0; ig < 2 * gj + 2; ++ig, ++G) {
            if ((G & (K2SLOTS - 1)) != slot) continue;   // uniform branch
            const unsigned qw = pack_word(row, gj, ig, xj, lane);
            const unsigned* pr = pm + ((size_t)G * NROWS_P + b * PP) * 64 + lane;
#pragma unroll
            for (int p = 0; p < PP; ++p)
                m[p] += __popc(qw ^ pr[p * 64]);   // v_xor + v_bcnt(acc)
        }
    }

    // lane reduction (butterfly over 64 lanes), then cross-wave via LDS
#pragma unroll
    for (int p = 0; p < PP; ++p) {
        unsigned v = m[p];
        for (int o = 32; o > 0; o >>= 1) v += __shfl_xor(v, o, 64);
        if (lane == 0) red[wave][p] = v;
    }
    __syncthreads();

    if (tid < PP) {
        unsigned tot = 0;
#pragma unroll
        for (int w = 0; w < K2WAVES; ++w) tot += red[w][tid];
        // block contribution; segments sum to 1 - 2*M/NPAIRS
        atomicAdd(&out[(size_t)bq * PP + tid],
                  1.0f / (float)K2SEGS - 2.0f * (float)tot * (1.0f / (float)NPAIRS));
    }
}

extern "C" void kernel_launch(void* const* d_in, const int* in_sizes, int n_in,
                              void* d_out, int out_size, void* d_ws, size_t ws_size,
                              hipStream_t stream) {
    const float* qfeat = (const float*)d_in[0];   // (B,Q,D) f32
    const float* pfeat = (const float*)d_in[1];   // (B,P,D) f32
    float* out = (float*)d_out;                   // (B,Q,P) f32
    unsigned* pm = (unsigned*)d_ws;               // 563,200 B of scratch

    // d_out is re-poisoned before every launch; blocks accumulate atomically.
    hipMemsetAsync(out, 0, (size_t)out_size * sizeof(float), stream);

    pack_p_kernel<<<dim3(NROWS_P, 8), 64, 0, stream>>>(pfeat, pm);
    kendall_kernel<<<BB * QQ * K2SEGS, 256, 0, stream>>>(qfeat, pm, out);
}